// Round 14
// baseline (982.907 us; speedup 1.0000x reference)
//
#include <hip/hip_runtime.h>
#include <math.h>

// GAT 3-layer (PyG GATConv + eval-BN + ReLU + log_softmax) on MI355X.
// Round 13: k_agg gets a TRUE 2-deep pipeline — ssrc prefetched 2 chunks
// ahead (linear addr, no deps), asrc gathered 1 chunk ahead using the
// s loaded last iteration (addr ready at issue). r9's same-body
// ssrc->asrc dependent prefetch REGRESSED (158->180us): the compiler had
// to stall mid-body on the ssrc result. k_agg2 reverted to verified r2.

static constexpr float BN_SCALE_F = 0.9999950000374996f; // 1/sqrt(1+1e-5)
static constexpr float NEG_SLOPE_F = 0.2f;

// ---------------------------------------------------------------- degree
__global__ void k_deg(const int* __restrict__ ei, int E, int N, int* __restrict__ deg) {
    int i = blockIdx.x * 256 + threadIdx.x;
    int M = E + N;
    if (i >= M) return;
    int d = (i < E) ? ei[(size_t)E + i] : (i - E);
    atomicAdd(&deg[d], 1);
}

// ---------------------------------------------------------------- scan (exclusive, 2048/block)
__global__ void k_scan1(const int* __restrict__ deg, int N, int* __restrict__ off,
                        int* __restrict__ bsum) {
    __shared__ int sh[2048];
    __shared__ int ts[256];
    int t = threadIdx.x;
    int base = blockIdx.x * 2048;
    for (int i = t; i < 2048; i += 256) sh[i] = (base + i < N) ? deg[base + i] : 0;
    __syncthreads();
    int loc[8];
    int tot = 0;
#pragma unroll
    for (int j = 0; j < 8; j++) { loc[j] = sh[t * 8 + j]; tot += loc[j]; }
    ts[t] = tot;
    __syncthreads();
    for (int d = 1; d < 256; d <<= 1) {
        int u = (t >= d) ? ts[t - d] : 0;
        __syncthreads();
        ts[t] += u;
        __syncthreads();
    }
    int run = (t > 0) ? ts[t - 1] : 0;
#pragma unroll
    for (int j = 0; j < 8; j++) {
        int idx = base + t * 8 + j;
        if (idx < N) off[idx] = run;
        run += loc[j];
    }
    if (t == 255) bsum[blockIdx.x] = ts[255];
}

__global__ void k_scan2(int* __restrict__ bsum, int nb) {
    __shared__ int ts[256];
    int t = threadIdx.x;
    int v = (t < nb) ? bsum[t] : 0;
    ts[t] = v;
    __syncthreads();
    for (int d = 1; d < 256; d <<= 1) {
        int u = (t >= d) ? ts[t - d] : 0;
        __syncthreads();
        ts[t] += u;
        __syncthreads();
    }
    if (t < nb) bsum[t] = ts[t] - v; // exclusive
}

__global__ void k_scan3(int* __restrict__ off, const int* __restrict__ bsum, int N, int M) {
    int i = blockIdx.x * 256 + threadIdx.x;
    if (i < N) off[i] += bsum[i >> 11];
    else if (i == N) off[N] = M;
}

// ---------------------------------------------------------------- scatter (sort by dst)
__global__ void k_scatter(const int* __restrict__ ei, int E, int N,
                          const int* __restrict__ off, int* __restrict__ cnt,
                          int* __restrict__ ssrc) {
    int i = blockIdx.x * 256 + threadIdx.x;
    int M = E + N;
    if (i >= M) return;
    int s, d;
    if (i < E) { s = ei[i]; d = ei[(size_t)E + i]; }
    else       { s = d = i - E; }
    int pos = off[d] + atomicAdd(&cnt[d], 1);
    ssrc[pos] = s;
}

// ---------------------------------------------------------------- GEMM  A[N,128] @ W[128,CC] -> out[N, OST]
// 512 threads, 128-row x NC-col tile, whole K=128 staged. 2 waves/SIMD.
template <int NC>
__global__ __launch_bounds__(512) void k_gemm(const float* __restrict__ A,
                                              const float* __restrict__ W, int N, int CC,
                                              int OST, float* __restrict__ out) {
    __shared__ float xs[128 * 128];
    __shared__ float ws[128 * NC];
    int tid = threadIdx.x;
    int row0 = blockIdx.x * 128;
    const float4* A4 = (const float4*)A;
    // x tile -> LDS, XOR-swizzled on k-quad by (row>>3)&3 (2-way conflict max = free)
#pragma unroll
    for (int i = 0; i < 8; i++) {
        int idx = tid + i * 512;
        int r = idx >> 5, c4 = idx & 31;
        int gr = row0 + r;
        float4 v = make_float4(0.f, 0.f, 0.f, 0.f);
        if (gr < N) v = A4[(size_t)gr * 32 + c4];
        int g = (r >> 3) & 3;
        *(float4*)&xs[r * 128 + ((c4 ^ g) << 2)] = v;
    }
    // W -> LDS (plain [k][c], zero-padded cols)
    constexpr int WIT = (128 * NC) / (512 * 4);
#pragma unroll
    for (int i = 0; i < WIT; i++) {
        int idx = tid + i * 512;
        int k = idx / (NC / 4);
        int c = (idx % (NC / 4)) * 4;
        float4 v;
        if (c + 3 < CC) {
            v = *(const float4*)&W[(size_t)k * CC + c];
        } else {
            float tmp[4];
#pragma unroll
            for (int j = 0; j < 4; j++) tmp[j] = (c + j < CC) ? W[(size_t)k * CC + c + j] : 0.f;
            v = make_float4(tmp[0], tmp[1], tmp[2], tmp[3]);
        }
        *(float4*)&ws[k * NC + c] = v;
    }
    __syncthreads();

    int ty = tid >> 4; // 32 row-groups of 4 rows
    int tx = tid & 15;
    constexpr int NH = NC / 64;
    float4 acc[4][NH];
#pragma unroll
    for (int r = 0; r < 4; r++)
#pragma unroll
        for (int h = 0; h < NH; h++) acc[r][h] = make_float4(0.f, 0.f, 0.f, 0.f);

#pragma unroll 2
    for (int k4 = 0; k4 < 32; k4++) {
        float4 xv[4];
#pragma unroll
        for (int r = 0; r < 4; r++) {
            int row = ty * 4 + r;
            int g = (row >> 3) & 3;
            xv[r] = *(const float4*)&xs[row * 128 + (((k4 ^ g) & 31) << 2)];
        }
        float4 wv[4][NH];
#pragma unroll
        for (int j = 0; j < 4; j++)
#pragma unroll
            for (int h = 0; h < NH; h++)
                wv[j][h] = *(const float4*)&ws[(k4 * 4 + j) * NC + tx * 4 + 64 * h];
#pragma unroll
        for (int r = 0; r < 4; r++) {
            const float* xf = (const float*)&xv[r];
#pragma unroll
            for (int j = 0; j < 4; j++) {
                float xsv = xf[j];
#pragma unroll
                for (int h = 0; h < NH; h++) {
                    acc[r][h].x += xsv * wv[j][h].x;
                    acc[r][h].y += xsv * wv[j][h].y;
                    acc[r][h].z += xsv * wv[j][h].z;
                    acc[r][h].w += xsv * wv[j][h].w;
                }
            }
        }
    }
#pragma unroll
    for (int r = 0; r < 4; r++) {
        int gr = row0 + ty * 4 + r;
        if (gr >= N) continue;
#pragma unroll
        for (int h = 0; h < NH; h++) {
            int c = tx * 4 + 64 * h;
            if (c < CC) *(float4*)&out[(size_t)gr * OST + c] = acc[r][h];
        }
    }
}

// ---------------------------------------------------------------- attention scores (H=4, C=32)
__global__ void k_att(const float* __restrict__ h, const float* __restrict__ att_s,
                      const float* __restrict__ att_d, int N, float* __restrict__ asrc,
                      float* __restrict__ adst) {
    int wid = (blockIdx.x * 256 + threadIdx.x) >> 6;
    int lane = threadIdx.x & 63;
    if (wid >= N) return;
    float2 hv = *(const float2*)&h[(size_t)wid * 128 + lane * 2];
    float2 as_ = *(const float2*)&att_s[lane * 2];
    float2 ad_ = *(const float2*)&att_d[lane * 2];
    float ps = hv.x * as_.x + hv.y * as_.y;
    float pd = hv.x * ad_.x + hv.y * ad_.y;
    for (int d = 1; d < 16; d <<= 1) {
        ps += __shfl_xor(ps, d);
        pd += __shfl_xor(pd, d);
    }
    if ((lane & 15) == 0) {
        int hd = lane >> 4;
        asrc[(size_t)wid * 4 + hd] = ps;
        adst[(size_t)wid * 4 + hd] = pd;
    }
}

// attention scores final layer (1 head, C=40), h2 stride 40
__global__ void k_att2(const float* __restrict__ h2, const float* __restrict__ as2,
                       const float* __restrict__ ad2, int N, float* __restrict__ asrc,
                       float* __restrict__ adst) {
    int wid = (blockIdx.x * 256 + threadIdx.x) >> 6;
    int lane = threadIdx.x & 63;
    if (wid >= N) return;
    float ps = 0.f, pd = 0.f;
    if (lane < 40) {
        float v = h2[(size_t)wid * 40 + lane];
        ps = v * as2[lane];
        pd = v * ad2[lane];
    }
    for (int d = 1; d < 64; d <<= 1) {
        ps += __shfl_xor(ps, d);
        pd += __shfl_xor(pd, d);
    }
    if (lane == 0) { asrc[wid] = ps; adst[wid] = pd; }
}

// ---------------------------------------------------------------- aggregation layers 0/1
// wave per node; chunked (16 edges) two-phase online softmax with a
// 2-DEEP pipeline: ssrc prefetched 2 chunks ahead (no deps), asrc
// gathered 1 chunk ahead from the s loaded last iteration (addr ready).
// No dependent-load waits inside the body. Unconditional clamped loads
// (end>beg always: self-loop) + select for validity — no exec branches.
__global__ void k_agg(const float* __restrict__ h, const float* __restrict__ asrc,
                      const float* __restrict__ adst, const int* __restrict__ ssrc,
                      const int* __restrict__ off, const float* __restrict__ bias,
                      const float* __restrict__ gamma, const float* __restrict__ beta,
                      float* __restrict__ out, int N) {
    int wid = (blockIdx.x * 256 + threadIdx.x) >> 6;
    int lane = threadIdx.x & 63;
    if (wid >= N) return;
    int beg = off[wid], end = off[wid + 1];
    int hd4 = lane & 3;  // scoring head
    int ei = lane >> 2;  // edge slot 0..15
    int hd = lane >> 4;  // accumulation head
    float adst_h4 = adst[(size_t)wid * 4 + hd4];
    int ch = lane * 2;
    float2 bias2 = *(const float2*)&bias[ch];   // hoisted epilogue params
    float2 g2    = *(const float2*)&gamma[ch];
    float2 be2   = *(const float2*)&beta[ch];
    float m = -INFINITY, ssum = 0.f;
    float accx0 = 0.f, accy0 = 0.f, accx1 = 0.f, accy1 = 0.f;
    const float* hrow = h + lane * 2;
    int last = end - 1; // valid: every node has a self-loop
    // ---- prologue: chunk0 fully scored, chunk1 ssrc loaded
    int j0 = beg + ei;
    int j1 = beg + 16 + ei;
    int s_c = ssrc[j0 <= last ? j0 : last];
    int s_n = ssrc[j1 <= last ? j1 : last];
    float a0 = asrc[(size_t)s_c * 4 + hd4];
    float e_c;
    {
        float t = a0 + adst_h4;
        t = (t > 0.f) ? t : t * NEG_SLOPE_F;
        e_c = (j0 < end) ? t : -INFINITY;
    }
    for (int c0 = beg; c0 < end; c0 += 16) {
        // ---- issue prefetches first (no dependencies on each other):
        int j2 = c0 + 32 + ei;                       // chunk c+2 ssrc
        int s_2 = ssrc[j2 <= last ? j2 : last];
        float a_n = asrc[(size_t)s_n * 4 + hd4];     // chunk c+1 asrc (s_n ready)
        // ---- phase A: chunk max / exp-sum on e_c (VALU only)
        float cmax = e_c;
        cmax = fmaxf(cmax, __shfl_xor(cmax, 4));
        cmax = fmaxf(cmax, __shfl_xor(cmax, 8));
        cmax = fmaxf(cmax, __shfl_xor(cmax, 16));
        cmax = fmaxf(cmax, __shfl_xor(cmax, 32));
        float mnew = fmaxf(m, cmax);
        float sc = __expf(m - mnew); // first chunk: exp(-inf)=0
        float p = __expf(e_c - mnew);  // invalid: exp(-inf)=0
        float psum = p;
        psum += __shfl_xor(psum, 4);
        psum += __shfl_xor(psum, 8);
        psum += __shfl_xor(psum, 16);
        psum += __shfl_xor(psum, 32);
        ssum = ssum * sc + psum;
        m = mnew;
        float sc_my = __shfl(sc, hd); // lane hd holds head hd's scale
        accx0 *= sc_my; accy0 *= sc_my;
        accx1 *= sc_my; accy1 *= sc_my;
        // ---- phase B: accumulate 16 edges (independent gathers)
        if (end - c0 >= 16) {
#pragma unroll
            for (int t = 0; t < 16; t++) {
                int sl = 4 * t + hd;
                int sj = __shfl(s_c, sl);
                float pj = __shfl(p, sl);
                float2 hv = *(const float2*)&hrow[(size_t)sj * 128];
                if (t & 1) { accx1 += pj * hv.x; accy1 += pj * hv.y; }
                else       { accx0 += pj * hv.x; accy0 += pj * hv.y; }
            }
        } else {
            int nv = end - c0;
#pragma unroll
            for (int t = 0; t < 16; t++) {
                if (t < nv) { // wave-uniform branch
                    int sl = 4 * t + hd;
                    int sj = __shfl(s_c, sl);
                    float pj = __shfl(p, sl);
                    float2 hv = *(const float2*)&hrow[(size_t)sj * 128];
                    if (t & 1) { accx1 += pj * hv.x; accy1 += pj * hv.y; }
                    else       { accx0 += pj * hv.x; accy0 += pj * hv.y; }
                }
            }
        }
        // ---- finish next chunk's score from a_n (arrived during A/B); rotate
        int j1b = c0 + 16 + ei;
        float tt = a_n + adst_h4;
        tt = (tt > 0.f) ? tt : tt * NEG_SLOPE_F;
        e_c = (j1b < end) ? tt : -INFINITY;
        s_c = s_n;
        s_n = s_2;
    }
    float s_h = __shfl(ssum, hd);
    float inv = 1.0f / (s_h + 1e-16f);
    float v0 = (accx0 + accx1) * inv + bias2.x;
    float v1 = (accy0 + accy1) * inv + bias2.y;
    v0 = g2.x * (v0 * BN_SCALE_F) + be2.x;
    v1 = g2.y * (v1 * BN_SCALE_F) + be2.y;
    v0 = fmaxf(v0, 0.f);
    v1 = fmaxf(v1, 0.f);
    *(float2*)&out[(size_t)wid * 128 + ch] = make_float2(v0, v1);
}

// ---------------------------------------------------------------- final aggregation (1 head, 40 ch)
// chunked (16 edges) two-phase online softmax (verified r2 form);
// lanes 0..15 score (all 4 16-lane groups redundantly); lane<40 owns one
// channel. Fused b2+blast+log_softmax.
__global__ void k_agg2(const float* __restrict__ h2, const float* __restrict__ asrc,
                       const float* __restrict__ adst, const int* __restrict__ ssrc,
                       const int* __restrict__ off, const float* __restrict__ b2,
                       const float* __restrict__ blast, float* __restrict__ out, int N) {
    int wid = (blockIdx.x * 256 + threadIdx.x) >> 6;
    int lane = threadIdx.x & 63;
    if (wid >= N) return;
    int beg = off[wid], end = off[wid + 1];
    float adn = adst[wid];
    int ei = lane & 15;
    int ch = lane;
    float m = -INFINITY, ssum = 0.f, acc0 = 0.f, acc1 = 0.f;
    for (int c0 = beg; c0 < end; c0 += 16) {
        int j = c0 + ei;
        bool valid = j < end;
        int s = 0;
        float e = -INFINITY;
        if (valid) {
            s = ssrc[j];
            float t = asrc[s] + adn;
            e = (t > 0.f) ? t : t * NEG_SLOPE_F;
        }
        float cmax = e;
        cmax = fmaxf(cmax, __shfl_xor(cmax, 1));
        cmax = fmaxf(cmax, __shfl_xor(cmax, 2));
        cmax = fmaxf(cmax, __shfl_xor(cmax, 4));
        cmax = fmaxf(cmax, __shfl_xor(cmax, 8));
        float mnew = fmaxf(m, cmax);
        float sc = __expf(m - mnew);
        float p = __expf(e - mnew);
        float psum = p;
        psum += __shfl_xor(psum, 1);
        psum += __shfl_xor(psum, 2);
        psum += __shfl_xor(psum, 4);
        psum += __shfl_xor(psum, 8);
        ssum = ssum * sc + psum;
        m = mnew;
        acc0 *= sc; acc1 *= sc;
        if (end - c0 >= 16) {
#pragma unroll
            for (int t = 0; t < 16; t++) {
                int sj = __shfl(s, t);
                float pj = __shfl(p, t);
                float hv = 0.f;
                if (ch < 40) hv = h2[(size_t)sj * 40 + ch];
                if (t & 1) acc1 += pj * hv;
                else       acc0 += pj * hv;
            }
        } else {
            int nv = end - c0;
#pragma unroll
            for (int t = 0; t < 16; t++) {
                if (t < nv) { // wave-uniform branch
                    int sj = __shfl(s, t);
                    float pj = __shfl(p, t);
                    float hv = 0.f;
                    if (ch < 40) hv = h2[(size_t)sj * 40 + ch];
                    if (t & 1) acc1 += pj * hv;
                    else       acc0 += pj * hv;
                }
            }
        }
    }
    float o = 0.f;
    if (ch < 40) o = (acc0 + acc1) / (ssum + 1e-16f) + b2[ch] + blast[ch];
    // log_softmax over 40 classes within the wave
    float lm = (ch < 40) ? o : -INFINITY;
    for (int d = 1; d < 64; d <<= 1) lm = fmaxf(lm, __shfl_xor(lm, d));
    float ex = (ch < 40) ? __expf(o - lm) : 0.f;
    float es = ex;
    for (int d = 1; d < 64; d <<= 1) es += __shfl_xor(es, d);
    if (ch < 40) out[(size_t)wid * 40 + ch] = o - lm - __logf(es);
}

// ================================================================ launch
extern "C" void kernel_launch(void* const* d_in, const int* in_sizes, int n_in, void* d_out,
                              int out_size, void* d_ws, size_t ws_size, hipStream_t stream) {
    const float* x   = (const float*)d_in[0];
    const int*   ei  = (const int*)d_in[1];
    const float* W0  = (const float*)d_in[2];
    const float* as0 = (const float*)d_in[3];
    const float* ad0 = (const float*)d_in[4];
    const float* b0  = (const float*)d_in[5];
    const float* g0  = (const float*)d_in[6];
    const float* be0 = (const float*)d_in[7];
    const float* W1  = (const float*)d_in[8];
    const float* as1 = (const float*)d_in[9];
    const float* ad1 = (const float*)d_in[10];
    const float* b1  = (const float*)d_in[11];
    const float* g1  = (const float*)d_in[12];
    const float* be1 = (const float*)d_in[13];
    const float* W2  = (const float*)d_in[14];
    const float* as2 = (const float*)d_in[15];
    const float* ad2 = (const float*)d_in[16];
    const float* b2  = (const float*)d_in[17];
    const float* bl  = (const float*)d_in[18];
    float* out = (float*)d_out;

    int N = in_sizes[0] / 128;
    int E = in_sizes[1] / 2;
    int M = E + N;

    // workspace carve (256B aligned)
    char* p = (char*)d_ws;
    auto carve = [&](size_t bytes) -> char* {
        char* q = p;
        p += (bytes + 255) & ~(size_t)255;
        return q;
    };
    float* bufA = (float*)carve((size_t)N * 128 * 4); // h (GEMM out)
    float* bufB = (float*)carve((size_t)N * 128 * 4); // layer out
    float* asrc = (float*)carve((size_t)N * 4 * 4);
    float* adst = (float*)carve((size_t)N * 4 * 4);
    int* deg  = (int*)carve((size_t)N * 4);
    int* off  = (int*)carve((size_t)(N + 1) * 4);
    int* bsum = (int*)carve(256 * 4);
    int* cnt  = (int*)carve((size_t)N * 4);
    int* ssrc = (int*)carve((size_t)M * 4);

    // ---- edge sort by dst (once, reused by all 3 layers)
    hipMemsetAsync(deg, 0, (size_t)N * 4, stream);
    hipMemsetAsync(cnt, 0, (size_t)N * 4, stream);
    k_deg<<<(M + 255) / 256, 256, 0, stream>>>(ei, E, N, deg);
    int NB = (N + 2047) / 2048;
    k_scan1<<<NB, 256, 0, stream>>>(deg, N, off, bsum);
    k_scan2<<<1, 256, 0, stream>>>(bsum, NB);
    k_scan3<<<(N + 256) / 256, 256, 0, stream>>>(off, bsum, N, M);
    k_scatter<<<(M + 255) / 256, 256, 0, stream>>>(ei, E, N, off, cnt, ssrc);

    int gblocks = (N + 127) / 128;
    int nodeblocks = (N + 3) / 4;

    // ---- layer 0: x @ W0 -> bufA; agg -> bufB (with b0 + BN + ReLU)
    k_gemm<128><<<gblocks, 512, 0, stream>>>(x, W0, N, 128, 128, bufA);
    k_att<<<nodeblocks, 256, 0, stream>>>(bufA, as0, ad0, N, asrc, adst);
    k_agg<<<nodeblocks, 256, 0, stream>>>(bufA, asrc, adst, ssrc, off, b0, g0, be0, bufB, N);
    // ---- layer 1
    k_gemm<128><<<gblocks, 512, 0, stream>>>(bufB, W1, N, 128, 128, bufA);
    k_att<<<nodeblocks, 256, 0, stream>>>(bufA, as1, ad1, N, asrc, adst);
    k_agg<<<nodeblocks, 256, 0, stream>>>(bufA, asrc, adst, ssrc, off, b1, g1, be1, bufB, N);
    // ---- layer 2 (heads=1, 40 cols): bufB @ W2 -> bufA (stride 40); final agg -> out
    k_gemm<64><<<gblocks, 512, 0, stream>>>(bufB, W2, N, 40, 40, bufA);
    k_att2<<<nodeblocks, 256, 0, stream>>>(bufA, as2, ad2, N, asrc, adst);
    k_agg2<<<nodeblocks, 256, 0, stream>>>(bufA, asrc, adst, ssrc, off, b2, bl, out, N);
}

// Round 15
// 891.920 us; speedup vs baseline: 1.1020x; 1.1020x over previous
//
#include <hip/hip_runtime.h>
#include <hip/hip_fp16.h>
#include <math.h>

// GAT 3-layer (PyG GATConv + eval-BN + ReLU + log_softmax) on MI355X.
// Round 14: k_agg REVERTED to verified r2 structure (both pipeline attempts
// r9/r13 regressed: 158 -> 180/174us; compiler+TLP already covers overlap).
// NEW: layers 0/1 store h in FP16 (GEMM epilogue packs half2) — halves the
// 468MB/dispatch gather traffic (512B->256B per edge row, still coalesced).
// Layer 2 path stays fp32. Hypothesis test: bytes-bound (dur ~halves) vs
// request-bound (dur unchanged -> pivot).

static constexpr float BN_SCALE_F = 0.9999950000374996f; // 1/sqrt(1+1e-5)
static constexpr float NEG_SLOPE_F = 0.2f;

// ---------------------------------------------------------------- degree
__global__ void k_deg(const int* __restrict__ ei, int E, int N, int* __restrict__ deg) {
    int i = blockIdx.x * 256 + threadIdx.x;
    int M = E + N;
    if (i >= M) return;
    int d = (i < E) ? ei[(size_t)E + i] : (i - E);
    atomicAdd(&deg[d], 1);
}

// ---------------------------------------------------------------- scan (exclusive, 2048/block)
__global__ void k_scan1(const int* __restrict__ deg, int N, int* __restrict__ off,
                        int* __restrict__ bsum) {
    __shared__ int sh[2048];
    __shared__ int ts[256];
    int t = threadIdx.x;
    int base = blockIdx.x * 2048;
    for (int i = t; i < 2048; i += 256) sh[i] = (base + i < N) ? deg[base + i] : 0;
    __syncthreads();
    int loc[8];
    int tot = 0;
#pragma unroll
    for (int j = 0; j < 8; j++) { loc[j] = sh[t * 8 + j]; tot += loc[j]; }
    ts[t] = tot;
    __syncthreads();
    for (int d = 1; d < 256; d <<= 1) {
        int u = (t >= d) ? ts[t - d] : 0;
        __syncthreads();
        ts[t] += u;
        __syncthreads();
    }
    int run = (t > 0) ? ts[t - 1] : 0;
#pragma unroll
    for (int j = 0; j < 8; j++) {
        int idx = base + t * 8 + j;
        if (idx < N) off[idx] = run;
        run += loc[j];
    }
    if (t == 255) bsum[blockIdx.x] = ts[255];
}

__global__ void k_scan2(int* __restrict__ bsum, int nb) {
    __shared__ int ts[256];
    int t = threadIdx.x;
    int v = (t < nb) ? bsum[t] : 0;
    ts[t] = v;
    __syncthreads();
    for (int d = 1; d < 256; d <<= 1) {
        int u = (t >= d) ? ts[t - d] : 0;
        __syncthreads();
        ts[t] += u;
        __syncthreads();
    }
    if (t < nb) bsum[t] = ts[t] - v; // exclusive
}

__global__ void k_scan3(int* __restrict__ off, const int* __restrict__ bsum, int N, int M) {
    int i = blockIdx.x * 256 + threadIdx.x;
    if (i < N) off[i] += bsum[i >> 11];
    else if (i == N) off[N] = M;
}

// ---------------------------------------------------------------- scatter (sort by dst)
__global__ void k_scatter(const int* __restrict__ ei, int E, int N,
                          const int* __restrict__ off, int* __restrict__ cnt,
                          int* __restrict__ ssrc) {
    int i = blockIdx.x * 256 + threadIdx.x;
    int M = E + N;
    if (i >= M) return;
    int s, d;
    if (i < E) { s = ei[i]; d = ei[(size_t)E + i]; }
    else       { s = d = i - E; }
    int pos = off[d] + atomicAdd(&cnt[d], 1);
    ssrc[pos] = s;
}

// ---------------------------------------------------------------- GEMM  A[N,128] @ W[128,CC] -> out[N, OST]
// 512 threads, 128-row x NC-col tile, whole K=128 staged. 2 waves/SIMD.
// HOUT: write fp16 (layers 0/1 h for the gather-bound agg) else fp32.
template <int NC, bool HOUT>
__global__ __launch_bounds__(512) void k_gemm(const float* __restrict__ A,
                                              const float* __restrict__ W, int N, int CC,
                                              int OST, void* __restrict__ outv) {
    __shared__ float xs[128 * 128];
    __shared__ float ws[128 * NC];
    int tid = threadIdx.x;
    int row0 = blockIdx.x * 128;
    const float4* A4 = (const float4*)A;
    // x tile -> LDS, XOR-swizzled on k-quad by (row>>3)&3 (2-way conflict max = free)
#pragma unroll
    for (int i = 0; i < 8; i++) {
        int idx = tid + i * 512;
        int r = idx >> 5, c4 = idx & 31;
        int gr = row0 + r;
        float4 v = make_float4(0.f, 0.f, 0.f, 0.f);
        if (gr < N) v = A4[(size_t)gr * 32 + c4];
        int g = (r >> 3) & 3;
        *(float4*)&xs[r * 128 + ((c4 ^ g) << 2)] = v;
    }
    // W -> LDS (plain [k][c], zero-padded cols)
    constexpr int WIT = (128 * NC) / (512 * 4);
#pragma unroll
    for (int i = 0; i < WIT; i++) {
        int idx = tid + i * 512;
        int k = idx / (NC / 4);
        int c = (idx % (NC / 4)) * 4;
        float4 v;
        if (c + 3 < CC) {
            v = *(const float4*)&W[(size_t)k * CC + c];
        } else {
            float tmp[4];
#pragma unroll
            for (int j = 0; j < 4; j++) tmp[j] = (c + j < CC) ? W[(size_t)k * CC + c + j] : 0.f;
            v = make_float4(tmp[0], tmp[1], tmp[2], tmp[3]);
        }
        *(float4*)&ws[k * NC + c] = v;
    }
    __syncthreads();

    int ty = tid >> 4; // 32 row-groups of 4 rows
    int tx = tid & 15;
    constexpr int NH = NC / 64;
    float4 acc[4][NH];
#pragma unroll
    for (int r = 0; r < 4; r++)
#pragma unroll
        for (int h = 0; h < NH; h++) acc[r][h] = make_float4(0.f, 0.f, 0.f, 0.f);

#pragma unroll 2
    for (int k4 = 0; k4 < 32; k4++) {
        float4 xv[4];
#pragma unroll
        for (int r = 0; r < 4; r++) {
            int row = ty * 4 + r;
            int g = (row >> 3) & 3;
            xv[r] = *(const float4*)&xs[row * 128 + (((k4 ^ g) & 31) << 2)];
        }
        float4 wv[4][NH];
#pragma unroll
        for (int j = 0; j < 4; j++)
#pragma unroll
            for (int h = 0; h < NH; h++)
                wv[j][h] = *(const float4*)&ws[(k4 * 4 + j) * NC + tx * 4 + 64 * h];
#pragma unroll
        for (int r = 0; r < 4; r++) {
            const float* xf = (const float*)&xv[r];
#pragma unroll
            for (int j = 0; j < 4; j++) {
                float xsv = xf[j];
#pragma unroll
                for (int h = 0; h < NH; h++) {
                    acc[r][h].x += xsv * wv[j][h].x;
                    acc[r][h].y += xsv * wv[j][h].y;
                    acc[r][h].z += xsv * wv[j][h].z;
                    acc[r][h].w += xsv * wv[j][h].w;
                }
            }
        }
    }
#pragma unroll
    for (int r = 0; r < 4; r++) {
        int gr = row0 + ty * 4 + r;
        if (gr >= N) continue;
#pragma unroll
        for (int h = 0; h < NH; h++) {
            int c = tx * 4 + 64 * h;
            if (c >= CC) continue;
            if (HOUT) {
                union { uint2 u; __half2 h2[2]; } pk;
                pk.h2[0] = __floats2half2_rn(acc[r][h].x, acc[r][h].y);
                pk.h2[1] = __floats2half2_rn(acc[r][h].z, acc[r][h].w);
                *(uint2*)&(((__half*)outv)[(size_t)gr * OST + c]) = pk.u;
            } else {
                *(float4*)&(((float*)outv)[(size_t)gr * OST + c]) = acc[r][h];
            }
        }
    }
}

// ---------------------------------------------------------------- attention scores (H=4, C=32), fp16 h
__global__ void k_att(const __half* __restrict__ h16, const float* __restrict__ att_s,
                      const float* __restrict__ att_d, int N, float* __restrict__ asrc,
                      float* __restrict__ adst) {
    int wid = (blockIdx.x * 256 + threadIdx.x) >> 6;
    int lane = threadIdx.x & 63;
    if (wid >= N) return;
    __half2 hv2 = ((const __half2*)h16)[(size_t)wid * 64 + lane];
    float2 hv = __half22float2(hv2);
    float2 as_ = *(const float2*)&att_s[lane * 2];
    float2 ad_ = *(const float2*)&att_d[lane * 2];
    float ps = hv.x * as_.x + hv.y * as_.y;
    float pd = hv.x * ad_.x + hv.y * ad_.y;
    for (int d = 1; d < 16; d <<= 1) {
        ps += __shfl_xor(ps, d);
        pd += __shfl_xor(pd, d);
    }
    if ((lane & 15) == 0) {
        int hd = lane >> 4;
        asrc[(size_t)wid * 4 + hd] = ps;
        adst[(size_t)wid * 4 + hd] = pd;
    }
}

// attention scores final layer (1 head, C=40), h2 stride 40 (fp32)
__global__ void k_att2(const float* __restrict__ h2, const float* __restrict__ as2,
                       const float* __restrict__ ad2, int N, float* __restrict__ asrc,
                       float* __restrict__ adst) {
    int wid = (blockIdx.x * 256 + threadIdx.x) >> 6;
    int lane = threadIdx.x & 63;
    if (wid >= N) return;
    float ps = 0.f, pd = 0.f;
    if (lane < 40) {
        float v = h2[(size_t)wid * 40 + lane];
        ps = v * as2[lane];
        pd = v * ad2[lane];
    }
    for (int d = 1; d < 64; d <<= 1) {
        ps += __shfl_xor(ps, d);
        pd += __shfl_xor(pd, d);
    }
    if (lane == 0) { asrc[wid] = ps; adst[wid] = pd; }
}

// ---------------------------------------------------------------- aggregation layers 0/1
// wave per node; chunked (16 edges) two-phase online softmax (verified r2
// structure, 158us fp32). h gathered as FP16 half2 (256B/row coalesced).
__global__ void k_agg(const __half* __restrict__ h16, const float* __restrict__ asrc,
                      const float* __restrict__ adst, const int* __restrict__ ssrc,
                      const int* __restrict__ off, const float* __restrict__ bias,
                      const float* __restrict__ gamma, const float* __restrict__ beta,
                      float* __restrict__ out, int N) {
    int wid = (blockIdx.x * 256 + threadIdx.x) >> 6;
    int lane = threadIdx.x & 63;
    if (wid >= N) return;
    int beg = off[wid], end = off[wid + 1];
    int hd4 = lane & 3;  // scoring head
    int ei = lane >> 2;  // edge slot 0..15
    int hd = lane >> 4;  // accumulation head
    float adst_h4 = adst[(size_t)wid * 4 + hd4];
    int ch = lane * 2;
    float2 bias2 = *(const float2*)&bias[ch];   // hoisted epilogue params
    float2 g2    = *(const float2*)&gamma[ch];
    float2 be2   = *(const float2*)&beta[ch];
    float m = -INFINITY, ssum = 0.f;
    float accx0 = 0.f, accy0 = 0.f, accx1 = 0.f, accy1 = 0.f;
    const __half2* hrow2 = (const __half2*)h16 + lane; // channels {2lane,2lane+1}
    for (int c0 = beg; c0 < end; c0 += 16) {
        int j = c0 + ei;
        bool valid = j < end;
        int s = 0;
        float e = -INFINITY;
        if (valid) {
            s = ssrc[j];
            float t = asrc[(size_t)s * 4 + hd4] + adst_h4;
            e = (t > 0.f) ? t : t * NEG_SLOPE_F;
        }
        float cmax = e;
        cmax = fmaxf(cmax, __shfl_xor(cmax, 4));
        cmax = fmaxf(cmax, __shfl_xor(cmax, 8));
        cmax = fmaxf(cmax, __shfl_xor(cmax, 16));
        cmax = fmaxf(cmax, __shfl_xor(cmax, 32));
        float mnew = fmaxf(m, cmax);
        float sc = __expf(m - mnew); // first chunk: exp(-inf)=0
        float p = __expf(e - mnew);  // invalid: exp(-inf)=0
        float psum = p;
        psum += __shfl_xor(psum, 4);
        psum += __shfl_xor(psum, 8);
        psum += __shfl_xor(psum, 16);
        psum += __shfl_xor(psum, 32);
        ssum = ssum * sc + psum;
        m = mnew;
        float sc_my = __shfl(sc, hd); // lane hd holds head hd's scale
        accx0 *= sc_my; accy0 *= sc_my;
        accx1 *= sc_my; accy1 *= sc_my;
        if (end - c0 >= 16) {
#pragma unroll
            for (int t = 0; t < 16; t++) {
                int sl = 4 * t + hd;
                int sj = __shfl(s, sl);
                float pj = __shfl(p, sl);
                float2 hv = __half22float2(hrow2[(size_t)sj * 64]);
                if (t & 1) { accx1 += pj * hv.x; accy1 += pj * hv.y; }
                else       { accx0 += pj * hv.x; accy0 += pj * hv.y; }
            }
        } else {
            int nv = end - c0;
#pragma unroll
            for (int t = 0; t < 16; t++) {
                if (t < nv) { // wave-uniform branch
                    int sl = 4 * t + hd;
                    int sj = __shfl(s, sl);
                    float pj = __shfl(p, sl);
                    float2 hv = __half22float2(hrow2[(size_t)sj * 64]);
                    if (t & 1) { accx1 += pj * hv.x; accy1 += pj * hv.y; }
                    else       { accx0 += pj * hv.x; accy0 += pj * hv.y; }
                }
            }
        }
    }
    float s_h = __shfl(ssum, hd);
    float inv = 1.0f / (s_h + 1e-16f);
    float v0 = (accx0 + accx1) * inv + bias2.x;
    float v1 = (accy0 + accy1) * inv + bias2.y;
    v0 = g2.x * (v0 * BN_SCALE_F) + be2.x;
    v1 = g2.y * (v1 * BN_SCALE_F) + be2.y;
    v0 = fmaxf(v0, 0.f);
    v1 = fmaxf(v1, 0.f);
    *(float2*)&out[(size_t)wid * 128 + ch] = make_float2(v0, v1);
}

// ---------------------------------------------------------------- final aggregation (1 head, 40 ch)
// chunked (16 edges) two-phase online softmax (verified r2 form, fp32);
// lanes 0..15 score (all 4 16-lane groups redundantly); lane<40 owns one
// channel. Fused b2+blast+log_softmax.
__global__ void k_agg2(const float* __restrict__ h2, const float* __restrict__ asrc,
                       const float* __restrict__ adst, const int* __restrict__ ssrc,
                       const int* __restrict__ off, const float* __restrict__ b2,
                       const float* __restrict__ blast, float* __restrict__ out, int N) {
    int wid = (blockIdx.x * 256 + threadIdx.x) >> 6;
    int lane = threadIdx.x & 63;
    if (wid >= N) return;
    int beg = off[wid], end = off[wid + 1];
    float adn = adst[wid];
    int ei = lane & 15;
    int ch = lane;
    float m = -INFINITY, ssum = 0.f, acc0 = 0.f, acc1 = 0.f;
    for (int c0 = beg; c0 < end; c0 += 16) {
        int j = c0 + ei;
        bool valid = j < end;
        int s = 0;
        float e = -INFINITY;
        if (valid) {
            s = ssrc[j];
            float t = asrc[s] + adn;
            e = (t > 0.f) ? t : t * NEG_SLOPE_F;
        }
        float cmax = e;
        cmax = fmaxf(cmax, __shfl_xor(cmax, 1));
        cmax = fmaxf(cmax, __shfl_xor(cmax, 2));
        cmax = fmaxf(cmax, __shfl_xor(cmax, 4));
        cmax = fmaxf(cmax, __shfl_xor(cmax, 8));
        float mnew = fmaxf(m, cmax);
        float sc = __expf(m - mnew);
        float p = __expf(e - mnew);
        float psum = p;
        psum += __shfl_xor(psum, 1);
        psum += __shfl_xor(psum, 2);
        psum += __shfl_xor(psum, 4);
        psum += __shfl_xor(psum, 8);
        ssum = ssum * sc + psum;
        m = mnew;
        acc0 *= sc; acc1 *= sc;
        if (end - c0 >= 16) {
#pragma unroll
            for (int t = 0; t < 16; t++) {
                int sj = __shfl(s, t);
                float pj = __shfl(p, t);
                float hv = 0.f;
                if (ch < 40) hv = h2[(size_t)sj * 40 + ch];
                if (t & 1) acc1 += pj * hv;
                else       acc0 += pj * hv;
            }
        } else {
            int nv = end - c0;
#pragma unroll
            for (int t = 0; t < 16; t++) {
                if (t < nv) { // wave-uniform branch
                    int sj = __shfl(s, t);
                    float pj = __shfl(p, t);
                    float hv = 0.f;
                    if (ch < 40) hv = h2[(size_t)sj * 40 + ch];
                    if (t & 1) acc1 += pj * hv;
                    else       acc0 += pj * hv;
                }
            }
        }
    }
    float o = 0.f;
    if (ch < 40) o = (acc0 + acc1) / (ssum + 1e-16f) + b2[ch] + blast[ch];
    // log_softmax over 40 classes within the wave
    float lm = (ch < 40) ? o : -INFINITY;
    for (int d = 1; d < 64; d <<= 1) lm = fmaxf(lm, __shfl_xor(lm, d));
    float ex = (ch < 40) ? __expf(o - lm) : 0.f;
    float es = ex;
    for (int d = 1; d < 64; d <<= 1) es += __shfl_xor(es, d);
    if (ch < 40) out[(size_t)wid * 40 + ch] = o - lm - __logf(es);
}

// ================================================================ launch
extern "C" void kernel_launch(void* const* d_in, const int* in_sizes, int n_in, void* d_out,
                              int out_size, void* d_ws, size_t ws_size, hipStream_t stream) {
    const float* x   = (const float*)d_in[0];
    const int*   ei  = (const int*)d_in[1];
    const float* W0  = (const float*)d_in[2];
    const float* as0 = (const float*)d_in[3];
    const float* ad0 = (const float*)d_in[4];
    const float* b0  = (const float*)d_in[5];
    const float* g0  = (const float*)d_in[6];
    const float* be0 = (const float*)d_in[7];
    const float* W1  = (const float*)d_in[8];
    const float* as1 = (const float*)d_in[9];
    const float* ad1 = (const float*)d_in[10];
    const float* b1  = (const float*)d_in[11];
    const float* g1  = (const float*)d_in[12];
    const float* be1 = (const float*)d_in[13];
    const float* W2  = (const float*)d_in[14];
    const float* as2 = (const float*)d_in[15];
    const float* ad2 = (const float*)d_in[16];
    const float* b2  = (const float*)d_in[17];
    const float* bl  = (const float*)d_in[18];
    float* out = (float*)d_out;

    int N = in_sizes[0] / 128;
    int E = in_sizes[1] / 2;
    int M = E + N;

    // workspace carve (256B aligned)
    char* p = (char*)d_ws;
    auto carve = [&](size_t bytes) -> char* {
        char* q = p;
        p += (bytes + 255) & ~(size_t)255;
        return q;
    };
    void* bufA = (void*)carve((size_t)N * 128 * 4);   // h16 (L0/L1) or h2 fp32 (L2)
    float* bufB = (float*)carve((size_t)N * 128 * 4); // layer out (fp32)
    float* asrc = (float*)carve((size_t)N * 4 * 4);
    float* adst = (float*)carve((size_t)N * 4 * 4);
    int* deg  = (int*)carve((size_t)N * 4);
    int* off  = (int*)carve((size_t)(N + 1) * 4);
    int* bsum = (int*)carve(256 * 4);
    int* cnt  = (int*)carve((size_t)N * 4);
    int* ssrc = (int*)carve((size_t)M * 4);

    // ---- edge sort by dst (once, reused by all 3 layers)
    hipMemsetAsync(deg, 0, (size_t)N * 4, stream);
    hipMemsetAsync(cnt, 0, (size_t)N * 4, stream);
    k_deg<<<(M + 255) / 256, 256, 0, stream>>>(ei, E, N, deg);
    int NB = (N + 2047) / 2048;
    k_scan1<<<NB, 256, 0, stream>>>(deg, N, off, bsum);
    k_scan2<<<1, 256, 0, stream>>>(bsum, NB);
    k_scan3<<<(N + 256) / 256, 256, 0, stream>>>(off, bsum, N, M);
    k_scatter<<<(M + 255) / 256, 256, 0, stream>>>(ei, E, N, off, cnt, ssrc);

    int gblocks = (N + 127) / 128;
    int nodeblocks = (N + 3) / 4;
    __half* h16 = (__half*)bufA;
    float* h2f = (float*)bufA;

    // ---- layer 0: x @ W0 -> h16; agg -> bufB (with b0 + BN + ReLU)
    k_gemm<128, true><<<gblocks, 512, 0, stream>>>(x, W0, N, 128, 128, bufA);
    k_att<<<nodeblocks, 256, 0, stream>>>(h16, as0, ad0, N, asrc, adst);
    k_agg<<<nodeblocks, 256, 0, stream>>>(h16, asrc, adst, ssrc, off, b0, g0, be0, bufB, N);
    // ---- layer 1
    k_gemm<128, true><<<gblocks, 512, 0, stream>>>(bufB, W1, N, 128, 128, bufA);
    k_att<<<nodeblocks, 256, 0, stream>>>(h16, as1, ad1, N, asrc, adst);
    k_agg<<<nodeblocks, 256, 0, stream>>>(h16, asrc, adst, ssrc, off, b1, g1, be1, bufB, N);
    // ---- layer 2 (heads=1, 40 cols, fp32): bufB @ W2 -> h2f (stride 40); final agg -> out
    k_gemm<64, false><<<gblocks, 512, 0, stream>>>(bufB, W2, N, 40, 40, bufA);
    k_att2<<<nodeblocks, 256, 0, stream>>>(h2f, as2, ad2, N, asrc, adst);
    k_agg2<<<nodeblocks, 256, 0, stream>>>(h2f, asrc, adst, ssrc, off, b2, bl, out, N);
}